// Round 8
// baseline (3829.891 us; speedup 1.0000x reference)
//
#include <hip/hip_runtime.h>
#include <hip/hip_bf16.h>
#include <cstdint>

// LSTM (relu activations), B=128 T=256 F=4 H=1024, gate order i,f,g,o.
// Persistent kernel: 256 WGs = 4 row-blocks (32 rows) x 64 hidden-blocks (16 units).
// v9 = v8(green, 1580us) + ONE-HOP sentinel-validated data exchange:
//  * h >= 0 always (sigmoid*relu) => every produced bf16-pair dword has sign
//    bits 0. ex[] is pre-filled 0x80 (sign bits 1) by our own memset each
//    launch. Consumer's ordinary b128 A-fragment loads (fresh address per t,
//    first touch) double as the sync: validate (orv & 0x80008000)==0.
//    Hit => ZERO protocol hops (v8 chain: store-ack + flag hop + poll + load).
//    ANY staleness reads sentinel -> detected, never silent.
//  * Producer: only the 2 sc1 data stores at end of step. vmcnt(0) + per-wave
//    flag publish (value t, meaning steps <t acked) moves to TOP of iter t,
//    overlapped with the sweep loads' own latency -> off the critical path.
//  * Sweep miss (rare): v8-proven flag wait (1 dword/lane spin, throttled,
//    no v7-style wide-spin congestion), then agent-atomic dword reload in a
//    validate-retry loop (correct under any cache-staleness; monotone
//    sentinel->valid => terminates). Deadlock-free by v2's induction.
//  * LDS audit closed: remaining 1.67e7 SQ_LDS_BANK_CONFLICT is ~2cy/instr
//    benign 2-way read accounting (m136: 2-way free). zpart b128 writes tile
//    all 32 banks. Init gather conflict-free at ULD=130 (delta matched 5e5).
// Fallback template<0>: v2-proven fp32-over-out flag protocol if ws too small.

#define B_SZ   128
#define T_SZ   256
#define H_SZ   1024
#define G_SZ   4096   // 4*H
#define ULD    130    // init staging leading dim (shorts): conflict-free gather

typedef __attribute__((ext_vector_type(8))) short short8;
typedef __attribute__((ext_vector_type(4))) float f32x4;

__device__ __forceinline__ short f2bf(float f) {
    union { float f; unsigned u; } a; a.f = f;
    unsigned r = a.u + 0x7fffu + ((a.u >> 16) & 1u);   // RNE
    return (short)(r >> 16);
}

__device__ __forceinline__ float sigmoidf_(float x) {
    return 1.0f / (1.0f + __expf(-x));
}

// 8 fp32 -> short8 bf16 (round half-up via +0x8000, pack hi16 pairs with v_perm)
__device__ __forceinline__ short8 pack8(f32x4 a, f32x4 b) {
    union { f32x4 v; unsigned u[4]; } ua, ub; ua.v = a; ub.v = b;
    union { short8 s; unsigned d[4]; } r;
    r.d[0] = __builtin_amdgcn_perm(ua.u[1] + 0x8000u, ua.u[0] + 0x8000u, 0x07060302u);
    r.d[1] = __builtin_amdgcn_perm(ua.u[3] + 0x8000u, ua.u[2] + 0x8000u, 0x07060302u);
    r.d[2] = __builtin_amdgcn_perm(ub.u[1] + 0x8000u, ub.u[2 - 2] + 0x8000u, 0x07060302u);
    r.d[2] = __builtin_amdgcn_perm(ub.u[1] + 0x8000u, ub.u[0] + 0x8000u, 0x07060302u);
    r.d[3] = __builtin_amdgcn_perm(ub.u[3] + 0x8000u, ub.u[2] + 0x8000u, 0x07060302u);
    return r.s;
}

template<int BF16EX>
__global__ __launch_bounds__(256, 1)
void lstm_persistent(const float* __restrict__ x, const float* __restrict__ W,
                     const float* __restrict__ U, const float* __restrict__ bias,
                     float* __restrict__ out, unsigned* __restrict__ flags,
                     short* __restrict__ ex)
{
    __shared__ __align__(16) char smem[66560];
    short* Ust   = (short*)smem;          // init staging: [256 k][130] bf16 (66560B)
    float* zpA   = (float*)smem;          // step partials buf 0 (32768B)
    float* zpB   = (float*)(smem + 32768);// buf 1

    const int tid  = threadIdx.x;
    const int bid  = blockIdx.x;
    const int rb   = bid >> 6;    // row block 0..3  (rows rb*32 .. +32)
    const int jb   = bid & 63;    // hidden block 0..63 (units jb*16 .. +16)
    const int w    = tid >> 6;    // wave 0..3 -> K slice [w*256, w*256+256)
    const int lane = tid & 63;
    const int q    = lane >> 4;   // quad 0..3
    const int n    = lane & 15;

    // ---------- init: build persistent B fragments from U (fp32 -> bf16) ----------
    short8 bfrag[8][4];           // [kk (32-k chunk within wave slice)][gate]
    for (int kc = 0; kc < 4; ++kc) {
        const int kbase = kc * 256;
        for (int i = tid; i < 256 * 64; i += 256) {
            int k = i >> 6, col = i & 63;
            int gcol = (col >> 4) * 1024 + jb * 16 + (col & 15);
            Ust[k * ULD + col] = f2bf(U[(size_t)(kbase + k) * G_SZ + gcol]);
        }
        __syncthreads();
        if (w == kc) {
            #pragma unroll
            for (int kk = 0; kk < 8; ++kk) {
                #pragma unroll
                for (int g = 0; g < 4; ++g) {
                    short8 bb;
                    #pragma unroll
                    for (int jj = 0; jj < 8; ++jj)
                        bb[jj] = Ust[(kk * 32 + q * 8 + jj) * ULD + g * 16 + n];
                    bfrag[kk][g] = bb;
                }
            }
        }
        __syncthreads();
    }

    // ---------- per-thread epilogue constants ----------
    const int row_l  = tid >> 4;          // 0..15
    const int hid_l  = tid & 15;
    const int hid_g  = jb * 16 + hid_l;
    const int row_g0 = rb * 32 + row_l;   // pair 0 (mt=0)
    const int row_g1 = row_g0 + 16;       // pair 1 (mt=1)
    const int qr = row_l >> 2, vr = row_l & 3;
    float Wr[4][4], br[4];
    #pragma unroll
    for (int g = 0; g < 4; ++g) {
        br[g] = bias[g * 1024 + hid_g];
        #pragma unroll
        for (int f = 0; f < 4; ++f)
            Wr[g][f] = W[(size_t)f * G_SZ + g * 1024 + hid_g];
    }
    float c0 = 0.f, c1 = 0.f;

    const int arow0 = rb * 32 + n;        // A-frag rows (mt 0/1 add 0/16)
    const int krow  = w * 256 + q * 8;
    // per-wave flags: flags[rb*256 + jb*4 + wave] = t  <=>  steps < t acked
    const unsigned* pollp = flags + rb * 256 + w * 64 + lane;   // 64 producer-waves of my K slice
    unsigned* pubp = flags + rb * 256 + jb * 4 + w;

    // ---------- time loop ----------
    for (int t = 0; t < T_SZ; ++t) {
        // x inputs (independent of h; issue early)
        f32x4 xv0 = *(const f32x4*)(x + ((size_t)row_g0 * T_SZ + t) * 4);
        f32x4 xv1 = *(const f32x4*)(x + ((size_t)row_g1 * T_SZ + t) * 4);

        // A fragments: h_{t-1}
        short8 af[8][2];
        if (t == 0) {
            short8 z = {};
            #pragma unroll
            for (int kk = 0; kk < 8; ++kk) { af[kk][0] = z; af[kk][1] = z; }
        } else if (BF16EX) {
            // ---- sweep-1: plain b128 loads (fresh lines -> LLC), sentinel-checked
            #pragma unroll
            for (int kk = 0; kk < 8; ++kk)
                #pragma unroll
                for (int mt = 0; mt < 2; ++mt)
                    af[kk][mt] = *(const short8*)(ex +
                        ((size_t)(arow0 + mt * 16) * T_SZ + (t - 1)) * H_SZ +
                        krow + kk * 32);
            // overlap: drain my step-(t-1) sc1 stores together with the sweep
            // loads' unavoidable latency, then publish my flag (value t).
            asm volatile("s_waitcnt vmcnt(0)" ::: "memory");
            if (lane == 0)
                __hip_atomic_store(pubp, (unsigned)t, __ATOMIC_RELAXED,
                                   __HIP_MEMORY_SCOPE_AGENT);
            // validate: any sentinel (sign bits set) anywhere?
            unsigned orv = 0u;
            #pragma unroll
            for (int kk = 0; kk < 8; ++kk)
                #pragma unroll
                for (int mt = 0; mt < 2; ++mt) {
                    union { short8 s; unsigned u[4]; } cv; cv.s = af[kk][mt];
                    orv |= cv.u[0] | cv.u[1] | cv.u[2] | cv.u[3];
                }
            if (!__all((int)((orv & 0x80008000u) == 0u))) {
                // ---- rare path: proven flag wait, then atomic reload+revalidate
                for (;;) {
                    unsigned v = __hip_atomic_load(pollp, __ATOMIC_RELAXED,
                                                   __HIP_MEMORY_SCOPE_AGENT);
                    if (__all((int)(v >= (unsigned)t))) break;
                    __builtin_amdgcn_s_sleep(2);
                }
                __atomic_signal_fence(__ATOMIC_ACQUIRE);
                for (;;) {
                    unsigned orv2 = 0u;
                    #pragma unroll
                    for (int kk = 0; kk < 8; ++kk)
                        #pragma unroll
                        for (int mt = 0; mt < 2; ++mt) {
                            const unsigned* pu = (const unsigned*)(ex +
                                ((size_t)(arow0 + mt * 16) * T_SZ + (t - 1)) * H_SZ +
                                krow + kk * 32);
                            union { short8 s; unsigned u[4]; } cv;
                            #pragma unroll
                            for (int d = 0; d < 4; ++d) {
                                cv.u[d] = __hip_atomic_load(pu + d, __ATOMIC_RELAXED,
                                                            __HIP_MEMORY_SCOPE_AGENT);
                                orv2 |= cv.u[d];
                            }
                            af[kk][mt] = cv.s;
                        }
                    if (__all((int)((orv2 & 0x80008000u) == 0u))) break;
                    __builtin_amdgcn_s_sleep(2);
                }
            }
        } else {
            // ---- fallback template: v2-proven flag protocol, fp32 via out ----
            for (;;) {
                unsigned v = __hip_atomic_load(pollp, __ATOMIC_RELAXED,
                                               __HIP_MEMORY_SCOPE_AGENT);
                if (__all((int)(v >= (unsigned)t))) break;
                __builtin_amdgcn_s_sleep(2);
            }
            __atomic_signal_fence(__ATOMIC_ACQUIRE);  // compiler-only ordering
            #pragma unroll
            for (int kk = 0; kk < 8; ++kk) {
                #pragma unroll
                for (int mt = 0; mt < 2; ++mt) {
                    const float* p = out +
                        ((size_t)(arow0 + mt * 16) * T_SZ + (t - 1)) * H_SZ +
                        krow + kk * 32;
                    f32x4 lo = *(const f32x4*)p;
                    f32x4 hi = *(const f32x4*)(p + 4);
                    af[kk][mt] = pack8(lo, hi);
                }
            }
        }

        f32x4 acc[2][4];
        #pragma unroll
        for (int mt = 0; mt < 2; ++mt)
            #pragma unroll
            for (int g = 0; g < 4; ++g)
                acc[mt][g] = (f32x4){0.f, 0.f, 0.f, 0.f};

        #pragma unroll
        for (int kk = 0; kk < 8; ++kk)
            #pragma unroll
            for (int mt = 0; mt < 2; ++mt)
                #pragma unroll
                for (int g = 0; g < 4; ++g)
                    acc[mt][g] = __builtin_amdgcn_mfma_f32_16x16x32_bf16(
                        af[kk][mt], bfrag[kk][g], acc[mt][g], 0, 0, 0);

        // K-split partials -> LDS, layout [blk][q][n][v]: contiguous b128 writes
        // (bank-tiling, conflict-free), scalar 2-way reads. Double-buffered.
        float* zp = (t & 1) ? zpB : zpA;
        #pragma unroll
        for (int mt = 0; mt < 2; ++mt)
            #pragma unroll
            for (int g = 0; g < 4; ++g)
                *(f32x4*)&zp[(((w * 2 + mt) * 4 + g) * 4 + q) * 64 + n * 4] =
                    acc[mt][g];
        __syncthreads();   // single barrier per step (write -> read, dbuf'd)

        // ---------- epilogue: sum partials, add x*W+b, gates, state update ----------
        float hn0, hn1;
        {
            float z[4];
            #pragma unroll
            for (int g = 0; g < 4; ++g) {
                float s = br[g];
                #pragma unroll
                for (int ww = 0; ww < 4; ++ww)
                    s += zp[(((ww * 2 + 0) * 4 + g) * 4 + qr) * 64 + hid_l * 4 + vr];
                s += xv0[0] * Wr[g][0] + xv0[1] * Wr[g][1] +
                     xv0[2] * Wr[g][2] + xv0[3] * Wr[g][3];
                z[g] = s;
            }
            float ig = sigmoidf_(z[0]), fg = sigmoidf_(z[1]);
            float gg = fmaxf(z[2], 0.f), og = sigmoidf_(z[3]);
            c0 = fg * c0 + ig * gg;
            hn0 = og * fmaxf(c0, 0.f);
        }
        {
            float z[4];
            #pragma unroll
            for (int g = 0; g < 4; ++g) {
                float s = br[g];
                #pragma unroll
                for (int ww = 0; ww < 4; ++ww)
                    s += zp[(((ww * 2 + 1) * 4 + g) * 4 + qr) * 64 + hid_l * 4 + vr];
                s += xv1[0] * Wr[g][0] + xv1[1] * Wr[g][1] +
                     xv1[2] * Wr[g][2] + xv1[3] * Wr[g][3];
                z[g] = s;
            }
            float ig = sigmoidf_(z[0]), fg = sigmoidf_(z[1]);
            float gg = fmaxf(z[2], 0.f), og = sigmoidf_(z[3]);
            c1 = fg * c1 + ig * gg;
            hn1 = og * fmaxf(c1, 0.f);
        }

        const size_t ob0 = ((size_t)row_g0 * T_SZ + t) * H_SZ + hid_g;
        const size_t ob1 = ((size_t)row_g1 * T_SZ + t) * H_SZ + hid_g;

        if (BF16EX) {
            // bf16 exchange: pair lanes pack 2 units -> u32, sc1 write-through.
            // The data IS the sync (sign bits 0). No vmcnt, no flag here.
            float o0 = __shfl_down(hn0, 1);
            float o1 = __shfl_down(hn1, 1);
            if ((hid_l & 1) == 0) {
                unsigned w0 = (unsigned)(unsigned short)f2bf(hn0) |
                              ((unsigned)(unsigned short)f2bf(o0) << 16);
                unsigned w1 = (unsigned)(unsigned short)f2bf(hn1) |
                              ((unsigned)(unsigned short)f2bf(o1) << 16);
                __hip_atomic_store((unsigned*)&ex[ob0], w0, __ATOMIC_RELAXED,
                                   __HIP_MEMORY_SCOPE_AGENT);
                __hip_atomic_store((unsigned*)&ex[ob1], w1, __ATOMIC_RELAXED,
                                   __HIP_MEMORY_SCOPE_AGENT);
            }
            // fp32 output: plain cached writeback, off the critical path
            out[ob0] = hn0;
            out[ob1] = hn1;
        } else {
            __hip_atomic_store((unsigned*)&out[ob0], __float_as_uint(hn0),
                               __ATOMIC_RELAXED, __HIP_MEMORY_SCOPE_AGENT);
            __hip_atomic_store((unsigned*)&out[ob1], __float_as_uint(hn1),
                               __ATOMIC_RELAXED, __HIP_MEMORY_SCOPE_AGENT);
            if (t != T_SZ - 1) {
                asm volatile("s_waitcnt vmcnt(0)" ::: "memory");
                if (lane == 0)
                    __hip_atomic_store(pubp, (unsigned)(t + 1),
                                       __ATOMIC_RELAXED, __HIP_MEMORY_SCOPE_AGENT);
            }
        }

        if (t == T_SZ - 1) {
            float* hlast = out + (size_t)B_SZ * T_SZ * H_SZ;
            float* clast = hlast + (size_t)B_SZ * H_SZ;
            hlast[(size_t)row_g0 * H_SZ + hid_g] = hn0;
            hlast[(size_t)row_g1 * H_SZ + hid_g] = hn1;
            clast[(size_t)row_g0 * H_SZ + hid_g] = c0;
            clast[(size_t)row_g1 * H_SZ + hid_g] = c1;
        }
    }
}

extern "C" void kernel_launch(void* const* d_in, const int* in_sizes, int n_in,
                              void* d_out, int out_size, void* d_ws, size_t ws_size,
                              hipStream_t stream) {
    const float* x    = (const float*)d_in[0];  // [128][256][4]
    const float* W    = (const float*)d_in[1];  // [4][4096]
    const float* U    = (const float*)d_in[2];  // [1024][4096]
    const float* bias = (const float*)d_in[3];  // [4096]
    float* out = (float*)d_out;                 // [128][256][1024] ++ h_last ++ c_last

    unsigned* flags = (unsigned*)d_ws;          // [4 rb][64 jb][4 wave] step flags
    short* ex = (short*)((char*)d_ws + 4096);   // bf16 h exchange [128][256][1024]

    const size_t exbytes = (size_t)B_SZ * T_SZ * H_SZ * sizeof(short);
    const size_t need = 4096 + exbytes;

    // zero the flags every launch
    hipMemsetAsync(d_ws, 0, 4096, stream);

    if (ws_size >= need) {
        // sentinel: 0x80808080 has both bf16 sign bits set; any produced dword
        // (two bf16 of h>=0) has both sign bits clear. Our own memset -> no
        // reliance on harness poison semantics.
        hipMemsetAsync(ex, 0x80, exbytes, stream);
        hipLaunchKernelGGL((lstm_persistent<1>), dim3(256), dim3(256), 0, stream,
                           x, W, U, bias, out, flags, ex);
    } else {
        hipLaunchKernelGGL((lstm_persistent<0>), dim3(256), dim3(256), 0, stream,
                           x, W, U, bias, out, flags, ex);
    }
}

// Round 9
// 1413.403 us; speedup vs baseline: 2.7097x; 2.7097x over previous
//
#include <hip/hip_runtime.h>
#include <hip/hip_bf16.h>
#include <cstdint>

// LSTM (relu activations), B=128 T=256 F=4 H=1024, gate order i,f,g,o.
// Persistent kernel: 256 WGs = 4 row-blocks (32 rows) x 64 hidden-blocks (16 units).
// v10 = v8 (green, 1580us) + split-half publish/poll pipelining:
//  * Producer row-halves (hn0 = rows 0..15 = consumers' mt=0; hn1 = rows
//    16..31 = mt=1) get separate flags. Producer: epiA -> store ex0 ->
//    epiB (overlaps ex0 ack) -> store ex1 -> vmcnt(1) [ex0 retired, in-order
//    retirement m135] -> flagA -> vmcnt(0) -> flagB -> plain out stores.
//    flagA ~600cy earlier than v8's single flag; flagB ~200cy later.
//  * Consumer: poll A -> issue af0 loads -> poll B OVERLAPS af0's ~700cy LLC
//    latency -> load af1. MFMAs mt-major so mt=0 starts as soon as af0 lands.
//  * x*W+b hoisted before the poll (off the post-barrier critical chain).
//  * v9 lesson baked in: NO speculative data sweeps (lockstep recurrence =>
//    data is never early; sentinel sweeps always miss and pull HBM).
// Everything else v8-verbatim: bf16 ex in d_ws (fresh addr/step, sc1),
// per-wave flags, zpart dbuf [blk][q][n][v] (b128 bank-tiled writes),
// ULD=130 init staging, ONE __syncthreads per step.
// Fallback template<0>: v2-proven fp32-over-out single-flag protocol.

#define B_SZ   128
#define T_SZ   256
#define H_SZ   1024
#define G_SZ   4096   // 4*H
#define ULD    130    // init staging leading dim (shorts): conflict-free gather

typedef __attribute__((ext_vector_type(8))) short short8;
typedef __attribute__((ext_vector_type(4))) float f32x4;

__device__ __forceinline__ short f2bf(float f) {
    union { float f; unsigned u; } a; a.f = f;
    unsigned r = a.u + 0x7fffu + ((a.u >> 16) & 1u);   // RNE
    return (short)(r >> 16);
}

__device__ __forceinline__ float sigmoidf_(float x) {
    return 1.0f / (1.0f + __expf(-x));
}

// 8 fp32 -> short8 bf16 (round half-up via +0x8000, pack hi16 pairs with v_perm)
__device__ __forceinline__ short8 pack8(f32x4 a, f32x4 b) {
    union { f32x4 v; unsigned u[4]; } ua, ub; ua.v = a; ub.v = b;
    union { short8 s; unsigned d[4]; } r;
    r.d[0] = __builtin_amdgcn_perm(ua.u[1] + 0x8000u, ua.u[0] + 0x8000u, 0x07060302u);
    r.d[1] = __builtin_amdgcn_perm(ua.u[3] + 0x8000u, ua.u[2] + 0x8000u, 0x07060302u);
    r.d[2] = __builtin_amdgcn_perm(ub.u[1] + 0x8000u, ub.u[0] + 0x8000u, 0x07060302u);
    r.d[3] = __builtin_amdgcn_perm(ub.u[3] + 0x8000u, ub.u[2] + 0x8000u, 0x07060302u);
    return r.s;
}

template<int BF16EX>
__global__ __launch_bounds__(256, 1)
void lstm_persistent(const float* __restrict__ x, const float* __restrict__ W,
                     const float* __restrict__ U, const float* __restrict__ bias,
                     float* __restrict__ out, unsigned* __restrict__ flagsA,
                     unsigned* __restrict__ flagsB, short* __restrict__ ex)
{
    __shared__ __align__(16) char smem[66560];
    short* Ust   = (short*)smem;          // init staging: [256 k][130] bf16 (66560B)
    float* zpA   = (float*)smem;          // step partials buf 0 (32768B)
    float* zpB   = (float*)(smem + 32768);// buf 1

    const int tid  = threadIdx.x;
    const int bid  = blockIdx.x;
    const int rb   = bid >> 6;    // row block 0..3  (rows rb*32 .. +32)
    const int jb   = bid & 63;    // hidden block 0..63 (units jb*16 .. +16)
    const int w    = tid >> 6;    // wave 0..3 -> K slice [w*256, w*256+256)
    const int lane = tid & 63;
    const int q    = lane >> 4;   // quad 0..3
    const int n    = lane & 15;

    // ---------- init: build persistent B fragments from U (fp32 -> bf16) ----------
    short8 bfrag[8][4];           // [kk (32-k chunk within wave slice)][gate]
    for (int kc = 0; kc < 4; ++kc) {
        const int kbase = kc * 256;
        for (int i = tid; i < 256 * 64; i += 256) {
            int k = i >> 6, col = i & 63;
            int gcol = (col >> 4) * 1024 + jb * 16 + (col & 15);
            Ust[k * ULD + col] = f2bf(U[(size_t)(kbase + k) * G_SZ + gcol]);
        }
        __syncthreads();
        if (w == kc) {
            #pragma unroll
            for (int kk = 0; kk < 8; ++kk) {
                #pragma unroll
                for (int g = 0; g < 4; ++g) {
                    short8 bb;
                    #pragma unroll
                    for (int jj = 0; jj < 8; ++jj)
                        bb[jj] = Ust[(kk * 32 + q * 8 + jj) * ULD + g * 16 + n];
                    bfrag[kk][g] = bb;
                }
            }
        }
        __syncthreads();
    }

    // ---------- per-thread epilogue constants ----------
    const int row_l  = tid >> 4;          // 0..15
    const int hid_l  = tid & 15;
    const int hid_g  = jb * 16 + hid_l;
    const int row_g0 = rb * 32 + row_l;   // pair 0 (mt=0)
    const int row_g1 = row_g0 + 16;       // pair 1 (mt=1)
    const int qr = row_l >> 2, vr = row_l & 3;
    float Wr[4][4], br[4];
    #pragma unroll
    for (int g = 0; g < 4; ++g) {
        br[g] = bias[g * 1024 + hid_g];
        #pragma unroll
        for (int f = 0; f < 4; ++f)
            Wr[g][f] = W[(size_t)f * G_SZ + g * 1024 + hid_g];
    }
    float c0 = 0.f, c1 = 0.f;

    const int arow0 = rb * 32 + n;        // A-frag rows (mt 0/1 add 0/16)
    const int krow  = w * 256 + q * 8;
    // per-wave flags: value t+1 <=> that wave's half for step t is acked
    const unsigned* pollpA = flagsA + rb * 256 + w * 64 + lane;
    const unsigned* pollpB = flagsB + rb * 256 + w * 64 + lane;
    unsigned* pubpA = flagsA + rb * 256 + jb * 4 + w;
    unsigned* pubpB = flagsB + rb * 256 + jb * 4 + w;

    // ---------- time loop ----------
    for (int t = 0; t < T_SZ; ++t) {
        // x inputs + x*W+b hoisted OFF the post-barrier chain
        f32x4 xv0 = *(const f32x4*)(x + ((size_t)row_g0 * T_SZ + t) * 4);
        f32x4 xv1 = *(const f32x4*)(x + ((size_t)row_g1 * T_SZ + t) * 4);
        float zb0[4], zb1[4];
        #pragma unroll
        for (int g = 0; g < 4; ++g) {
            zb0[g] = br[g] + xv0[0] * Wr[g][0] + xv0[1] * Wr[g][1] +
                     xv0[2] * Wr[g][2] + xv0[3] * Wr[g][3];
            zb1[g] = br[g] + xv1[0] * Wr[g][0] + xv1[1] * Wr[g][1] +
                     xv1[2] * Wr[g][2] + xv1[3] * Wr[g][3];
        }

        // A fragments: h_{t-1}
        short8 af[8][2];
        if (t == 0) {
            short8 z = {};
            #pragma unroll
            for (int kk = 0; kk < 8; ++kk) { af[kk][0] = z; af[kk][1] = z; }
        } else if (BF16EX) {
            // ---- poll half A (rows 0..15 of my rb) ----
            for (;;) {
                unsigned v = __hip_atomic_load(pollpA, __ATOMIC_RELAXED,
                                               __HIP_MEMORY_SCOPE_AGENT);
                if (__all((int)(v >= (unsigned)t))) break;
                __builtin_amdgcn_s_sleep(2);
            }
            __atomic_signal_fence(__ATOMIC_ACQUIRE);
            #pragma unroll
            for (int kk = 0; kk < 8; ++kk)
                af[kk][0] = *(const short8*)(ex +
                    ((size_t)arow0 * T_SZ + (t - 1)) * H_SZ + krow + kk * 32);
            asm volatile("" ::: "memory");   // pin af0 loads before the B-poll
            // ---- poll half B overlaps af0's LLC load latency ----
            for (;;) {
                unsigned v = __hip_atomic_load(pollpB, __ATOMIC_RELAXED,
                                               __HIP_MEMORY_SCOPE_AGENT);
                if (__all((int)(v >= (unsigned)t))) break;
                __builtin_amdgcn_s_sleep(2);
            }
            __atomic_signal_fence(__ATOMIC_ACQUIRE);
            #pragma unroll
            for (int kk = 0; kk < 8; ++kk)
                af[kk][1] = *(const short8*)(ex +
                    ((size_t)(arow0 + 16) * T_SZ + (t - 1)) * H_SZ + krow + kk * 32);
        } else {
            // ---- fallback: v2-proven single-flag protocol, fp32 via out ----
            for (;;) {
                unsigned v = __hip_atomic_load(pollpA, __ATOMIC_RELAXED,
                                               __HIP_MEMORY_SCOPE_AGENT);
                if (__all((int)(v >= (unsigned)t))) break;
                __builtin_amdgcn_s_sleep(2);
            }
            __atomic_signal_fence(__ATOMIC_ACQUIRE);
            #pragma unroll
            for (int kk = 0; kk < 8; ++kk) {
                #pragma unroll
                for (int mt = 0; mt < 2; ++mt) {
                    const float* p = out +
                        ((size_t)(arow0 + mt * 16) * T_SZ + (t - 1)) * H_SZ +
                        krow + kk * 32;
                    f32x4 lo = *(const f32x4*)p;
                    f32x4 hi = *(const f32x4*)(p + 4);
                    af[kk][mt] = pack8(lo, hi);
                }
            }
        }

        f32x4 acc[2][4];
        #pragma unroll
        for (int mt = 0; mt < 2; ++mt)
            #pragma unroll
            for (int g = 0; g < 4; ++g)
                acc[mt][g] = (f32x4){0.f, 0.f, 0.f, 0.f};

        // mt-major: mt=0 MFMAs start as soon as af0 arrives
        #pragma unroll
        for (int kk = 0; kk < 8; ++kk)
            #pragma unroll
            for (int g = 0; g < 4; ++g)
                acc[0][g] = __builtin_amdgcn_mfma_f32_16x16x32_bf16(
                    af[kk][0], bfrag[kk][g], acc[0][g], 0, 0, 0);
        #pragma unroll
        for (int kk = 0; kk < 8; ++kk)
            #pragma unroll
            for (int g = 0; g < 4; ++g)
                acc[1][g] = __builtin_amdgcn_mfma_f32_16x16x32_bf16(
                    af[kk][1], bfrag[kk][g], acc[1][g], 0, 0, 0);

        // K-split partials -> LDS, layout [blk][q][n][v]: contiguous b128 writes
        // (bank-tiled, conflict-free), scalar 2-way reads. Double-buffered.
        float* zp = (t & 1) ? zpB : zpA;
        #pragma unroll
        for (int mt = 0; mt < 2; ++mt)
            #pragma unroll
            for (int g = 0; g < 4; ++g)
                *(f32x4*)&zp[(((w * 2 + mt) * 4 + g) * 4 + q) * 64 + n * 4] =
                    acc[mt][g];
        __syncthreads();   // single barrier per step (write -> read, dbuf'd)

        const size_t ob0 = ((size_t)row_g0 * T_SZ + t) * H_SZ + hid_g;
        const size_t ob1 = ((size_t)row_g1 * T_SZ + t) * H_SZ + hid_g;

        // ---------- epilogue half A (rows 0..15) -> store ex0 immediately ----------
        float hn0;
        {
            float z[4];
            #pragma unroll
            for (int g = 0; g < 4; ++g) {
                float s = zb0[g];
                #pragma unroll
                for (int ww = 0; ww < 4; ++ww)
                    s += zp[(((ww * 2 + 0) * 4 + g) * 4 + qr) * 64 + hid_l * 4 + vr];
                z[g] = s;
            }
            float ig = sigmoidf_(z[0]), fg = sigmoidf_(z[1]);
            float gg = fmaxf(z[2], 0.f), og = sigmoidf_(z[3]);
            c0 = fg * c0 + ig * gg;
            hn0 = og * fmaxf(c0, 0.f);
        }
        if (BF16EX) {
            float o0 = __shfl_down(hn0, 1);
            if ((hid_l & 1) == 0) {
                unsigned d0 = (unsigned)(unsigned short)f2bf(hn0) |
                              ((unsigned)(unsigned short)f2bf(o0) << 16);
                __hip_atomic_store((unsigned*)&ex[ob0], d0, __ATOMIC_RELAXED,
                                   __HIP_MEMORY_SCOPE_AGENT);
            }
        }

        // ---------- epilogue half B (rows 16..31), overlaps ex0's ack ----------
        float hn1;
        {
            float z[4];
            #pragma unroll
            for (int g = 0; g < 4; ++g) {
                float s = zb1[g];
                #pragma unroll
                for (int ww = 0; ww < 4; ++ww)
                    s += zp[(((ww * 2 + 1) * 4 + g) * 4 + qr) * 64 + hid_l * 4 + vr];
                z[g] = s;
            }
            float ig = sigmoidf_(z[0]), fg = sigmoidf_(z[1]);
            float gg = fmaxf(z[2], 0.f), og = sigmoidf_(z[3]);
            c1 = fg * c1 + ig * gg;
            hn1 = og * fmaxf(c1, 0.f);
        }

        if (BF16EX) {
            float o1 = __shfl_down(hn1, 1);
            if ((hid_l & 1) == 0) {
                unsigned d1 = (unsigned)(unsigned short)f2bf(hn1) |
                              ((unsigned)(unsigned short)f2bf(o1) << 16);
                __hip_atomic_store((unsigned*)&ex[ob1], d1, __ATOMIC_RELAXED,
                                   __HIP_MEMORY_SCOPE_AGENT);
            }
            if (t != T_SZ - 1) {
                // counted vmcnt: ex0 retired (in-order) -> flagA; then ex1 -> flagB
                asm volatile("s_waitcnt vmcnt(1)" ::: "memory");
                if (lane == 0)
                    __hip_atomic_store(pubpA, (unsigned)(t + 1),
                                       __ATOMIC_RELAXED, __HIP_MEMORY_SCOPE_AGENT);
                asm volatile("s_waitcnt vmcnt(0)" ::: "memory");
                if (lane == 0)
                    __hip_atomic_store(pubpB, (unsigned)(t + 1),
                                       __ATOMIC_RELAXED, __HIP_MEMORY_SCOPE_AGENT);
            }
            // fp32 output: plain cached writeback, off the critical path
            out[ob0] = hn0;
            out[ob1] = hn1;
        } else {
            __hip_atomic_store((unsigned*)&out[ob0], __float_as_uint(hn0),
                               __ATOMIC_RELAXED, __HIP_MEMORY_SCOPE_AGENT);
            __hip_atomic_store((unsigned*)&out[ob1], __float_as_uint(hn1),
                               __ATOMIC_RELAXED, __HIP_MEMORY_SCOPE_AGENT);
            if (t != T_SZ - 1) {
                asm volatile("s_waitcnt vmcnt(0)" ::: "memory");
                if (lane == 0)
                    __hip_atomic_store(pubpA, (unsigned)(t + 1),
                                       __ATOMIC_RELAXED, __HIP_MEMORY_SCOPE_AGENT);
            }
        }

        if (t == T_SZ - 1) {
            float* hlast = out + (size_t)B_SZ * T_SZ * H_SZ;
            float* clast = hlast + (size_t)B_SZ * H_SZ;
            hlast[(size_t)row_g0 * H_SZ + hid_g] = hn0;
            hlast[(size_t)row_g1 * H_SZ + hid_g] = hn1;
            clast[(size_t)row_g0 * H_SZ + hid_g] = c0;
            clast[(size_t)row_g1 * H_SZ + hid_g] = c1;
        }
    }
}

extern "C" void kernel_launch(void* const* d_in, const int* in_sizes, int n_in,
                              void* d_out, int out_size, void* d_ws, size_t ws_size,
                              hipStream_t stream) {
    const float* x    = (const float*)d_in[0];  // [128][256][4]
    const float* W    = (const float*)d_in[1];  // [4][4096]
    const float* U    = (const float*)d_in[2];  // [1024][4096]
    const float* bias = (const float*)d_in[3];  // [4096]
    float* out = (float*)d_out;                 // [128][256][1024] ++ h_last ++ c_last

    unsigned* flagsA = (unsigned*)d_ws;                  // [4 rb][64 jb][4 w]
    unsigned* flagsB = (unsigned*)((char*)d_ws + 4096);  // [4 rb][64 jb][4 w]
    short* ex = (short*)((char*)d_ws + 8192);            // bf16 h exchange

    // zero both flag arrays (ws is poisoned before every timed launch)
    hipMemsetAsync(d_ws, 0, 8192, stream);

    const size_t need = 8192 + (size_t)B_SZ * T_SZ * H_SZ * sizeof(short);
    if (ws_size >= need) {
        hipLaunchKernelGGL((lstm_persistent<1>), dim3(256), dim3(256), 0, stream,
                           x, W, U, bias, out, flagsA, flagsB, ex);
    } else {
        hipLaunchKernelGGL((lstm_persistent<0>), dim3(256), dim3(256), 0, stream,
                           x, W, U, bias, out, flagsA, flagsB, ex);
    }
}